// Round 7
// baseline (311.489 us; speedup 1.0000x reference)
//
#include <hip/hip_runtime.h>
#include <hip/hip_bf16.h>
#include <math.h>

// N=25000, E=400000, S=8, NB=8, RMAX=5, EMB=16, MULS=(8,4,4), DIMS=(1,3,5), WNUM=1024
// g[e,u] = sum_p c[e,p] * ( sum_k h3[e,k] gw4[k, col(p,u)] + gb4[col(p,u)] )
// out[a, f(u,m)] = (1/cnt[a]) * sum_{e: dst=a} alpha * g[e,u] * sh[e, m]
//
// Pipeline (5 nodes): memset -> setup(prep+rank0) -> mid(MLP+scan) -> edge_fused
// -> gather. r7 change: edge_fused processes TWO 64-edge tiles per wave,
// interleaved at the inner loop: B-operands (weights) are shared by both tiles
// (1 B-load feeds 2 MFMAs, W4pk L2 traffic halves) and every dependency gap has
// a second independent chain (intra-wave ILP, since occupancy-packaging failed).

typedef __attribute__((ext_vector_type(8))) short short8;
typedef __attribute__((ext_vector_type(4))) float f32x4;

#define EROW 28   // floats per edge row: g[16] + sh[9] + pad (112 B, 16-aligned)

__device__ __forceinline__ float silu_f(float x) {
    float e = __expf(-x);
    return x * __builtin_amdgcn_rcpf(1.0f + e);
}
__device__ __forceinline__ float silu_exact(float x) { return x / (1.0f + __expf(-x)); }

__device__ __forceinline__ unsigned short bf16r(float f) {
    union { float f; unsigned u; } v; v.f = f;
    return (unsigned short)((v.u + 0x7fffu + ((v.u >> 16) & 1u)) >> 16);
}
__device__ __forceinline__ unsigned pkcvt(float lo, float hi) {
    union { __hip_bfloat162 h; unsigned u; } v;
    v.h = __float22bfloat162_rn(float2{lo, hi});
    return v.u;
}
__device__ __forceinline__ float bflo(unsigned u) {
    union { unsigned u; float f; } v; v.u = u << 16; return v.f;
}
__device__ __forceinline__ float bfhi(unsigned u) {
    union { unsigned u; float f; } v; v.u = u & 0xffff0000u; return v.f;
}

// ---------------- setup: prep permutes + rank0 ONLY (lean, high occupancy) ----
__global__ __launch_bounds__(256) void setup_kernel(
    const float* __restrict__ gw4, const float* __restrict__ gb4,
    const float* __restrict__ gw1, const float* __restrict__ gw2,
    const float* __restrict__ gw3,
    unsigned short* __restrict__ W4pk, unsigned short* __restrict__ gw1Tp,
    unsigned short* __restrict__ gw2T, unsigned short* __restrict__ gw3T,
    unsigned short* __restrict__ gb4T2,
    const int* __restrict__ edge_dst, int* __restrict__ cnt_i,
    int* __restrict__ rank0, int n_edges)
{
    int b = blockIdx.x;
    if (b < 300) {
        int idx = b * 256 + threadIdx.x;
        if (idx < 65536) {
            int k = idx >> 10, col = idx & 1023;
            int p, u;
            if (col < 512)      { p = col >> 3;          u = col & 7; }
            else if (col < 768) { p = (col - 512) >> 2;  u = 8 + ((col - 512) & 3); }
            else                { p = (col - 768) >> 2;  u = 12 + ((col - 768) & 3); }
            W4pk[p * 1024 + u * 64 + k] = bf16r(gw4[idx]);
        } else if (idx < 67584) {
            int t = idx - 65536; int n = t >> 5, k = t & 31;
            gw1Tp[t] = (k < 8) ? bf16r(gw1[k * 64 + n]) : (unsigned short)0;
        } else if (idx < 71680) {
            int t = idx - 67584; int n = t >> 6, k = t & 63;
            gw2T[t] = bf16r(gw2[k * 64 + n]);
        } else if (idx < 75776) {
            int t = idx - 71680; int n = t >> 6, k = t & 63;
            gw3T[t] = bf16r(gw3[k * 64 + n]);
        } else if (idx < 76800) {
            int t = idx - 75776; int u = t >> 6, p = t & 63;
            int colb = (u < 8) ? (p * 8 + u)
                     : (u < 12) ? (512 + p * 4 + (u - 8))
                                : (768 + p * 4 + (u - 12));
            gb4T2[t] = bf16r(gb4[colb]);
        }
        return;
    }
    int e = (b - 300) * 256 + threadIdx.x;
    if (e < n_edges) rank0[e] = atomicAdd(&cnt_i[edge_dst[e]], 1);
}

// ---------------- mid: atom-MLP blocks + one scan block (one launch) ---------
__global__ __launch_bounds__(1024) void mid_kernel(
    const float* __restrict__ atom_table, const int* __restrict__ A,
    const float* __restrict__ fw1, const float* __restrict__ fb1,
    const float* __restrict__ fw2, const float* __restrict__ fb2,
    const float* __restrict__ fw3, const float* __restrict__ fb3,
    float* __restrict__ Ai, int n_atoms, int na_blk,
    const int* __restrict__ cnt, int* __restrict__ off)
{
    __shared__ int s[1024];
    int tid = threadIdx.x;
    int b = blockIdx.x;

    if (b < na_blk) {
        int n = b * 1024 + tid;
        if (n >= n_atoms) return;
        const float4* ap = (const float4*)(atom_table + (size_t)A[n] * 16);
        float4 a0 = ap[0], a1 = ap[1], a2 = ap[2], a3 = ap[3];
        float a[16] = {a0.x, a0.y, a0.z, a0.w, a1.x, a1.y, a1.z, a1.w,
                       a2.x, a2.y, a2.z, a2.w, a3.x, a3.y, a3.z, a3.w};

        float h2[32];
#pragma unroll
        for (int t = 0; t < 32; ++t) h2[t] = fb2[t];

#pragma unroll 4
        for (int k = 0; k < 64; ++k) {
            float h = fb1[k];
#pragma unroll
            for (int j = 0; j < 16; ++j) h += a[j] * fw1[j * 64 + k];
            h = silu_exact(h);
#pragma unroll
            for (int t = 0; t < 32; ++t) h2[t] += h * fw2[k * 32 + t];
        }

        float o[8];
#pragma unroll
        for (int t = 0; t < 8; ++t) o[t] = fb3[t];
#pragma unroll 4
        for (int k = 0; k < 32; ++k) {
            float x = silu_exact(h2[k]);
#pragma unroll
            for (int t = 0; t < 8; ++t) o[t] += x * fw3[k * 8 + t];
        }
        float* op = Ai + (size_t)n * 8;
        *(float4*)op       = float4{o[0], o[1], o[2], o[3]};
        *(float4*)(op + 4) = float4{o[4], o[5], o[6], o[7]};
        return;
    }

    // ---- scan block: off = exclusive prefix sum of cnt
    int chunk = (n_atoms + 1023) / 1024;
    int start = tid * chunk;
    int end = min(start + chunk, n_atoms);
    int sum = 0;
    for (int i = start; i < end; ++i) sum += cnt[i];
    s[tid] = sum;
    __syncthreads();
    for (int d = 1; d < 1024; d <<= 1) {
        int v = (tid >= d) ? s[tid - d] : 0;
        __syncthreads();
        s[tid] += v;
        __syncthreads();
    }
    int run = (tid == 0) ? 0 : s[tid - 1];
    for (int i = start; i < end; ++i) {
        off[i] = run; run += cnt[i];
    }
    if (tid == 1023) off[n_atoms] = s[1023];
}

// ---------------- fused edge kernel: ONE WAVE, TWO 64-edge tiles --------------
// Tiles 2b, 2b+1 interleaved: shared B-operands, doubled accumulation chains.
// LDS [2][8448] wave-private, ZERO barriers. Phantom tail tile is benign
// (clamped edges write duplicate data; epilogue guards real writes).
__global__ __launch_bounds__(64, 2) void edge_fused(
    const float* __restrict__ pos, const float* __restrict__ edge_shifts,
    const float* __restrict__ cell, const int* __restrict__ batch,
    const int* __restrict__ edge_src, const int* __restrict__ edge_dst,
    const float* __restrict__ Ai,
    const float* __restrict__ gb1, const float* __restrict__ gb2,
    const float* __restrict__ gb3,
    const unsigned short* __restrict__ gw1Tp, const unsigned short* __restrict__ gw2T,
    const unsigned short* __restrict__ gw3T,
    const unsigned short* __restrict__ W4pk, const unsigned short* __restrict__ gb4T2,
    const int* __restrict__ off, const int* __restrict__ rank0,
    float* __restrict__ erow, int n_edges)
{
    // per tile: phase A h-buffer [64][66] shorts / phase B c-buffer [32][66] u32
    __shared__ __align__(16) char smem[2][8448];

    int lane = threadIdx.x;
    int quad = lane >> 4, col = lane & 15;

    int src[2], dst[2], rk[2];
    uint4 em4[2];

#pragma unroll
    for (int t = 0; t < 2; ++t) {
        int eb = (blockIdx.x * 2 + t) * 64;
        int ec = min(eb + lane, n_edges - 1);
        src[t] = edge_src[ec]; dst[t] = edge_dst[ec];
        rk[t] = off[dst[t]] + rank0[ec];

        // phase 0: geometry -> emb (regs) + sh (straight to erow, float4)
        int b = batch[src[t]];
        const float* C = cell + b * 9;
        float es0 = edge_shifts[ec * 3 + 0];
        float es1 = edge_shifts[ec * 3 + 1];
        float es2 = edge_shifts[ec * 3 + 2];
        float vx = pos[dst[t] * 3 + 0] - pos[src[t] * 3 + 0] + es0 * C[0] + es1 * C[3] + es2 * C[6];
        float vy = pos[dst[t] * 3 + 1] - pos[src[t] * 3 + 1] + es0 * C[1] + es1 * C[4] + es2 * C[7];
        float vz = pos[dst[t] * 3 + 2] - pos[src[t] * 3 + 2] + es0 * C[2] + es1 * C[5] + es2 * C[8];
        float r2 = vx * vx + vy * vy + vz * vz + 1e-12f;
        float r = sqrtf(r2);
        float inv = 1.0f / r;
        float x = vx * inv, y = vy * inv, z = vz * inv;

        float xr = fminf(r * 0.2f, 1.0f);
        float cutoff = (r <= 5.0f) ? 2.8284271247461903f : 0.0f;
        float em[8];
#pragma unroll
        for (int k = 0; k < 8; ++k) {
            float d = (xr - (float)k * (1.0f / 7.0f)) * 7.0f;
            em[k] = __expf(-0.5f * d * d) * cutoff;
        }
        em4[t] = make_uint4(pkcvt(em[0], em[1]), pkcvt(em[2], em[3]),
                            pkcvt(em[4], em[5]), pkcvt(em[6], em[7]));

        const float s3 = 1.7320508075688772f;
        const float s5 = 2.23606797749979f;
        const float s15 = 3.872983346207417f;
        float* op = erow + (size_t)rk[t] * EROW + 16;
        *(float4*)op = float4{1.0f, s3 * x, s3 * y, s3 * z};
        *(float4*)(op + 4) = float4{s15 * x * y, s15 * y * z,
                                    0.5f * s5 * (2.0f * z * z - x * x - y * y),
                                    s15 * x * z};
        op[8] = 0.5f * s15 * (x * x - y * y);
    }

    // ---- phase A, layer 1: A-frags via shfl (quad 0 holds k<8, rest zero);
    //      B-operand shared by both tiles.
#pragma unroll
    for (int s = 0; s < 4; ++s) {
        int sl = s * 16 + col;   // lane owning this edge
        short8 aT[2];
#pragma unroll
        for (int t = 0; t < 2; ++t) {
            union { unsigned u[4]; short8 s8; } ua;
            ua.u[0] = (unsigned)__shfl((int)em4[t].x, sl, 64);
            ua.u[1] = (unsigned)__shfl((int)em4[t].y, sl, 64);
            ua.u[2] = (unsigned)__shfl((int)em4[t].z, sl, 64);
            ua.u[3] = (unsigned)__shfl((int)em4[t].w, sl, 64);
            short8 a = ua.s8;
            if (quad != 0) {
                short8 z = {0, 0, 0, 0, 0, 0, 0, 0};
                a = z;
            }
            aT[t] = a;
        }
#pragma unroll
        for (int nt = 0; nt < 4; ++nt) {
            int n = nt * 16 + col;
            short8 b = *(const short8*)(gw1Tp + n * 32 + quad * 8);
            float bb = gb1[n];
#pragma unroll
            for (int t = 0; t < 2; ++t) {
                f32x4 d = {bb, bb, bb, bb};
                d = __builtin_amdgcn_mfma_f32_16x16x32_bf16(aT[t], b, d, 0, 0, 0);
                unsigned u01 = pkcvt(silu_f(d[0]), silu_f(d[1]));
                unsigned u23 = pkcvt(silu_f(d[2]), silu_f(d[3]));
                unsigned short* bp2 = (unsigned short*)smem[t] + (s * 16 + quad * 4) * 66 + n;
                bp2[0]   = (unsigned short)(u01 & 0xffffu);
                bp2[66]  = (unsigned short)(u01 >> 16);
                bp2[132] = (unsigned short)(u23 & 0xffffu);
                bp2[198] = (unsigned short)(u23 >> 16);
            }
        }
    }

    // ---- phase A, layers 2 and 3 (wave-private LDS round trips, B shared)
#pragma unroll 1
    for (int layer = 0; layer < 2; ++layer) {
        const unsigned short* WT = layer ? gw3T : gw2T;
        const float* gb = layer ? gb3 : gb2;

        short8 a0[2][4], a1[2][4];
#pragma unroll
        for (int t = 0; t < 2; ++t) {
            const unsigned short* hh = (const unsigned short*)smem[t];
#pragma unroll
            for (int s = 0; s < 4; ++s) {
                a0[t][s] = *(const short8*)&hh[(s * 16 + col) * 66 + quad * 8];
                a1[t][s] = *(const short8*)&hh[(s * 16 + col) * 66 + 32 + quad * 8];
            }
        }

#pragma unroll
        for (int nt = 0; nt < 4; ++nt) {
            int n = nt * 16 + col;
            short8 b0 = *(const short8*)(WT + n * 64 + quad * 8);
            short8 b1 = *(const short8*)(WT + n * 64 + 32 + quad * 8);
            float bb = gb[n];
#pragma unroll
            for (int t = 0; t < 2; ++t) {
#pragma unroll
                for (int s = 0; s < 4; ++s) {
                    f32x4 d = {bb, bb, bb, bb};
                    d = __builtin_amdgcn_mfma_f32_16x16x32_bf16(a0[t][s], b0, d, 0, 0, 0);
                    d = __builtin_amdgcn_mfma_f32_16x16x32_bf16(a1[t][s], b1, d, 0, 0, 0);
                    unsigned u01 = pkcvt(silu_f(d[0]), silu_f(d[1]));
                    unsigned u23 = pkcvt(silu_f(d[2]), silu_f(d[3]));
                    unsigned short* bp2 = (unsigned short*)smem[t] + (s * 16 + quad * 4) * 66 + n;
                    bp2[0]   = (unsigned short)(u01 & 0xffffu);
                    bp2[66]  = (unsigned short)(u01 >> 16);
                    bp2[132] = (unsigned short)(u23 & 0xffffu);
                    bp2[198] = (unsigned short)(u23 >> 16);
                }
            }
        }
    }

    // ---- h3 A-frags to registers (in-order DS pipe: reads precede c overwrites)
    short8 aH0[2][4], aH1[2][4];
#pragma unroll
    for (int t = 0; t < 2; ++t) {
        const unsigned short* hh = (const unsigned short*)smem[t];
#pragma unroll
        for (int s = 0; s < 4; ++s) {
            aH0[t][s] = *(const short8*)&hh[(s * 16 + col) * 66 + quad * 8];
            aH1[t][s] = *(const short8*)&hh[(s * 16 + col) * 66 + 32 + quad * 8];
        }
    }

    // ---- phase B prep: pair-packed c[pp][e] bf16x2 (overwrites h-buffers)
#pragma unroll
    for (int t = 0; t < 2; ++t) {
        unsigned* s_c2 = (unsigned*)smem[t];
        const float4* asp = (const float4*)(Ai + (size_t)src[t] * 8);
        float4 A0 = asp[0], A1 = asp[1];
        const float4* adp = (const float4*)(Ai + (size_t)dst[t] * 8);
        float4 B0 = adp[0], B1 = adp[1];
        float as[8] = {A0.x, A0.y, A0.z, A0.w, A1.x, A1.y, A1.z, A1.w};
        float ad[8] = {B0.x, B0.y, B0.z, B0.w, B1.x, B1.y, B1.z, B1.w};
#pragma unroll
        for (int pp = 0; pp < 32; ++pp) {
            int p = pp * 2;
            float av = as[p >> 3];
            s_c2[pp * 66 + lane] = pkcvt(av * ad[p & 7], av * ad[(p & 7) + 1]);
        }
    }

    // ---- bias GEMM: g = c @ gb4T2^T  (A from c-buffers, K=64; B shared)
    f32x4 g[2][4];
    {
        const unsigned short* bbp = gb4T2 + col * 64 + quad * 8;
        short8 b0 = *(const short8*)bbp;
        short8 b1 = *(const short8*)(bbp + 32);
        f32x4 zero4 = {0.0f, 0.0f, 0.0f, 0.0f};
#pragma unroll
        for (int t = 0; t < 2; ++t) {
            const unsigned* s_c2 = (const unsigned*)smem[t];
#pragma unroll
            for (int s = 0; s < 4; ++s) {
                int ebase = s * 16 + col;
                union { unsigned u[4]; short8 s8; } ua, ub;
#pragma unroll
                for (int q = 0; q < 4; ++q) ua.u[q] = s_c2[(quad * 4 + q) * 66 + ebase];
#pragma unroll
                for (int q = 0; q < 4; ++q) ub.u[q] = s_c2[(16 + quad * 4 + q) * 66 + ebase];
                f32x4 d = __builtin_amdgcn_mfma_f32_16x16x32_bf16(ua.s8, b0, zero4, 0, 0, 0);
                g[t][s] = __builtin_amdgcn_mfma_f32_16x16x32_bf16(ub.s8, b1, d, 0, 0, 0);
            }
        }
    }

    // ---- main p-loop: 2-pair-deep shared B prefetch, both tiles interleaved
    const unsigned short* wb = W4pk + col * 64 + quad * 8;
    const char* cb0 = (const char*)smem[0] + quad * 16;
    const char* cb1 = (const char*)smem[1] + quad * 16;
    f32x4 zero4 = {0.0f, 0.0f, 0.0f, 0.0f};

    short8 Pb0[2], Pb1[2], Qb0[2], Qb1[2];
    Pb0[0] = *(const short8*)(wb);
    Pb1[0] = *(const short8*)(wb + 32);
    Qb0[0] = *(const short8*)(wb + 1024);
    Qb1[0] = *(const short8*)(wb + 1056);
    Pb0[1] = *(const short8*)(wb + 2048);
    Pb1[1] = *(const short8*)(wb + 2080);
    Qb0[1] = *(const short8*)(wb + 3072);
    Qb1[1] = *(const short8*)(wb + 3104);

#pragma unroll 2
    for (int pp = 0; pp < 32; ++pp) {
        int slot = pp & 1;
        short8 b0 = Pb0[slot], b1 = Pb1[slot], e0 = Qb0[slot], e1 = Qb1[slot];
        // prefetch pair pp+2 (tail overruns into gw1Tp/gw2T — harmless)
        const unsigned short* nw = wb + (2 * pp + 4) * 1024;
        Pb0[slot] = *(const short8*)(nw);
        Pb1[slot] = *(const short8*)(nw + 32);
        Qb0[slot] = *(const short8*)(nw + 1024);
        Qb1[slot] = *(const short8*)(nw + 1056);

#pragma unroll
        for (int t = 0; t < 2; ++t) {
            const char* cbase = t ? cb1 : cb0;
#pragma unroll
            for (int s = 0; s < 4; ++s) {
                uint4 cc = *(const uint4*)(cbase + pp * 264 + s * 64);
                f32x4 x1 = __builtin_amdgcn_mfma_f32_16x16x32_bf16(aH0[t][s], b0, zero4, 0, 0, 0);
                f32x4 d  = __builtin_amdgcn_mfma_f32_16x16x32_bf16(aH1[t][s], b1, x1, 0, 0, 0);
                f32x4 x2 = __builtin_amdgcn_mfma_f32_16x16x32_bf16(aH0[t][s], e0, zero4, 0, 0, 0);
                f32x4 d2 = __builtin_amdgcn_mfma_f32_16x16x32_bf16(aH1[t][s], e1, x2, 0, 0, 0);
                const unsigned* cu = (const unsigned*)&cc;
#pragma unroll
                for (int r = 0; r < 4; ++r) {
                    unsigned u = cu[r];
                    g[t][s][r] += bflo(u) * d[r];
                    g[t][s][r] += bfhi(u) * d2[r];
                }
            }
        }
    }

    // ---- epilogue: CSR-ordered row writes, rank via shfl (per tile)
    const float alpha = 0.125f;
#pragma unroll
    for (int t = 0; t < 2; ++t) {
        int eb = (blockIdx.x * 2 + t) * 64;
#pragma unroll
        for (int s = 0; s < 4; ++s) {
#pragma unroll
            for (int r = 0; r < 4; ++r) {
                int el = s * 16 + quad * 4 + r;
                int rkv = __shfl(rk[t], el, 64);
                if (eb + el < n_edges)
                    erow[(size_t)rkv * EROW + col] = alpha * g[t][s][r];
            }
        }
    }
}

// ---------------- gather: wave per atom, LDS-staged coalesced rows ----------
__global__ __launch_bounds__(256) void gather_kernel(
    const int* __restrict__ off, const float* __restrict__ erow,
    float* __restrict__ out, int n_atoms)
{
    __shared__ float s_rows[4][8][30];
    int w = threadIdx.x >> 6, lane = threadIdx.x & 63;
    int a = blockIdx.x * 4 + w;
    if (a >= n_atoms) return;
    int beg = off[a], end = off[a + 1];

    int f = min(lane, 39);
    int u, shi;
    if (f < 8)       { u = f;                 shi = 0; }
    else if (f < 20) { u = 8 + (f - 8) / 3;   shi = 1 + (f - 8) % 3; }
    else             { u = 12 + (f - 20) / 5; shi = 4 + (f - 20) % 5; }

    int rsub = lane >> 3, csub = lane & 7;   // lane stages row rsub, dwords csub*4..+4
    float val = 0.0f;
    for (int i = beg; i < end; i += 8) {
        int nr = min(8, end - i);
        int ri = i + rsub;
        if (csub < 7) {   // 28 dwords per row
            float4 v = (ri < end) ? *(const float4*)(erow + (size_t)ri * EROW + csub * 4)
                                  : float4{0.0f, 0.0f, 0.0f, 0.0f};
            *(float2*)&s_rows[w][rsub][csub * 4]     = float2{v.x, v.y};
            *(float2*)&s_rows[w][rsub][csub * 4 + 2] = float2{v.z, v.w};
        }
        // wave-private LDS slice: compiler waitcnt suffices, no barrier
#pragma unroll
        for (int j = 0; j < 8; ++j) {
            float prod = s_rows[w][j][u] * s_rows[w][j][16 + shi];
            val += (j < nr) ? prod : 0.0f;
        }
    }
    if (lane < 40) {
        float c = (float)max(end - beg, 1);
        out[(size_t)a * 40 + lane] = val / c;
    }
}

static inline size_t align256(size_t x) { return (x + 255) & ~(size_t)255; }

extern "C" void kernel_launch(void* const* d_in, const int* in_sizes, int n_in,
                              void* d_out, int out_size, void* d_ws, size_t ws_size,
                              hipStream_t stream)
{
    const float* pos         = (const float*)d_in[0];
    const float* edge_shifts = (const float*)d_in[1];
    const float* cell        = (const float*)d_in[2];
    const float* atom_table  = (const float*)d_in[3];
    const float* fw1 = (const float*)d_in[4];
    const float* fb1 = (const float*)d_in[5];
    const float* fw2 = (const float*)d_in[6];
    const float* fb2 = (const float*)d_in[7];
    const float* fw3 = (const float*)d_in[8];
    const float* fb3 = (const float*)d_in[9];
    const float* gw1 = (const float*)d_in[10];
    const float* gb1 = (const float*)d_in[11];
    const float* gw2 = (const float*)d_in[12];
    const float* gb2 = (const float*)d_in[13];
    const float* gw3 = (const float*)d_in[14];
    const float* gb3 = (const float*)d_in[15];
    const float* gw4 = (const float*)d_in[16];
    const float* gb4 = (const float*)d_in[17];
    const int* A        = (const int*)d_in[18];
    const int* batch    = (const int*)d_in[19];
    const int* edge_src = (const int*)d_in[20];
    const int* edge_dst = (const int*)d_in[21];

    int n_atoms = in_sizes[18];
    int n_edges = in_sizes[20];

    char* w = (char*)d_ws;
    float* Ai = (float*)w;                      w += align256((size_t)n_atoms * 8 * 4);
    int* cnt_i = (int*)w;                       w += align256((size_t)n_atoms * 4);
    int* off = (int*)w;                         w += align256((size_t)(n_atoms + 1) * 4);
    int* rank0 = (int*)w;                       w += align256((size_t)n_edges * 4);
    unsigned short* W4pk = (unsigned short*)w;  w += align256((size_t)65536 * 2);
    unsigned short* gw1Tp = (unsigned short*)w; w += align256((size_t)2048 * 2);
    unsigned short* gw2T = (unsigned short*)w;  w += align256((size_t)4096 * 2);
    unsigned short* gw3T = (unsigned short*)w;  w += align256((size_t)4096 * 2);
    unsigned short* gb4T2 = (unsigned short*)w; w += align256((size_t)1024 * 2);
    float* erow = (float*)w;                    w += align256((size_t)n_edges * EROW * 4);

    float* out = (float*)d_out;

    hipMemsetAsync(cnt_i, 0, sizeof(int) * (size_t)n_atoms, stream);

    int e_blk = (n_edges + 255) / 256;
    setup_kernel<<<300 + e_blk, 256, 0, stream>>>(
        gw4, gb4, gw1, gw2, gw3, W4pk, gw1Tp, gw2T, gw3T, gb4T2,
        edge_dst, cnt_i, rank0, n_edges);

    int na_blk = (n_atoms + 1023) / 1024;
    mid_kernel<<<na_blk + 1, 1024, 0, stream>>>(
        atom_table, A, fw1, fb1, fw2, fb2, fw3, fb3,
        Ai, n_atoms, na_blk, cnt_i, off);

    int n_tiles = (n_edges + 63) / 64;
    edge_fused<<<(n_tiles + 1) / 2, 64, 0, stream>>>(
        pos, edge_shifts, cell, batch, edge_src, edge_dst, Ai,
        gb1, gb2, gb3, gw1Tp, gw2T, gw3T, W4pk, gb4T2, off, rank0, erow, n_edges);

    gather_kernel<<<(n_atoms + 3) / 4, 256, 0, stream>>>(off, erow, out, n_atoms);
}